// Round 1
// baseline (565.028 us; speedup 1.0000x reference)
//
#include <hip/hip_runtime.h>

// MultiHeadAttention: B=4, S=2048, D=1024, H=16, DK=64
// Pipeline: cvt x->bf16; transpose weights->bf16 [N][K]; QKV GEMM (MFMA bf16);
// flash attention (causal, online softmax); output GEMM -> fp32.

typedef __attribute__((ext_vector_type(8))) short short8;
typedef __attribute__((ext_vector_type(4))) float floatx4;
typedef __attribute__((ext_vector_type(4))) unsigned short ushort4v;

__device__ __forceinline__ unsigned short f2bf(float f) {
    unsigned int u = __float_as_uint(f);
    unsigned int r = (u + 0x7fffu + ((u >> 16) & 1u)) >> 16;
    return (unsigned short)r;
}

// ---------------- convert x (fp32 -> bf16) ----------------
__global__ void cvtx_kernel(const float* __restrict__ x, unsigned short* __restrict__ xb) {
    int i = (blockIdx.x * 256 + threadIdx.x) * 4;
    float4 v = *(const float4*)&x[i];
    ushort4v o;
    o.x = f2bf(v.x); o.y = f2bf(v.y); o.z = f2bf(v.z); o.w = f2bf(v.w);
    *(ushort4v*)&xb[i] = o;
}

// ---------------- transpose + convert weight: w[K][N] fp32 -> wt[N][K] bf16 ----------------
__global__ void wtrans_kernel(const float* __restrict__ w, unsigned short* __restrict__ wt) {
    __shared__ float t[32][33];
    int kb = blockIdx.y * 32, nb = blockIdx.x * 32;
    int col = threadIdx.x & 31, rw = threadIdx.x >> 5; // rw in 0..7
#pragma unroll
    for (int i = 0; i < 4; i++) {
        int row = rw + i * 8;
        t[row][col] = w[(kb + row) * 1024 + nb + col];
    }
    __syncthreads();
#pragma unroll
    for (int i = 0; i < 4; i++) {
        int row = rw + i * 8;
        wt[(nb + row) * 1024 + kb + col] = f2bf(t[col][row]);
    }
}

// ---------------- shared GEMM mainloop: C[128x128] = A[M][K] * Bt[N][K]^T ----------------
// A, Bt bf16 row-major (K contiguous). LDS row stride 40 elems (pad 8: bank-spread + 16B align).
#define LDST 40

__device__ __forceinline__ void gemm_core(const unsigned short* __restrict__ A,
                                          const unsigned short* __restrict__ Bt,
                                          unsigned short* As, unsigned short* Bs,
                                          int m0, int n0, int K, floatx4 (&acc)[4][4]) {
    int tid = threadIdx.x;
    int lane = tid & 63, wave = tid >> 6;
    int wr = wave >> 1, wc = wave & 1;
    int quad = lane >> 4, l15 = lane & 15;
    floatx4 zero4 = {0.f, 0.f, 0.f, 0.f};
#pragma unroll
    for (int i = 0; i < 4; i++)
#pragma unroll
        for (int j = 0; j < 4; j++) acc[i][j] = zero4;

    for (int k0 = 0; k0 < K; k0 += 32) {
#pragma unroll
        for (int p = 0; p < 2; p++) {
            int c = p * 256 + tid;       // 0..511
            int row = c >> 2;            // 0..127
            int col8 = (c & 3) * 8;      // 0,8,16,24
            *(short8*)&As[row * LDST + col8] = *(const short8*)&A[(m0 + row) * K + k0 + col8];
            *(short8*)&Bs[row * LDST + col8] = *(const short8*)&Bt[(n0 + row) * K + k0 + col8];
        }
        __syncthreads();
        short8 af[4], bf[4];
#pragma unroll
        for (int mt = 0; mt < 4; mt++)
            af[mt] = *(short8*)&As[(wr * 64 + mt * 16 + l15) * LDST + quad * 8];
#pragma unroll
        for (int nt = 0; nt < 4; nt++)
            bf[nt] = *(short8*)&Bs[(wc * 64 + nt * 16 + l15) * LDST + quad * 8];
#pragma unroll
        for (int mt = 0; mt < 4; mt++)
#pragma unroll
            for (int nt = 0; nt < 4; nt++)
                acc[mt][nt] = __builtin_amdgcn_mfma_f32_16x16x32_bf16(af[mt], bf[nt], acc[mt][nt], 0, 0, 0);
        __syncthreads();
    }
}

// ---------------- QKV GEMM: out permuted to [B,H,S,DK] bf16 ----------------
__global__ __launch_bounds__(256) void gemm_qkv_kernel(
    const unsigned short* __restrict__ xb,
    const unsigned short* __restrict__ wtq, const unsigned short* __restrict__ wtk,
    const unsigned short* __restrict__ wtv,
    const float* __restrict__ bq, const float* __restrict__ bk, const float* __restrict__ bv,
    unsigned short* __restrict__ qo, unsigned short* __restrict__ ko, unsigned short* __restrict__ vo) {
    __shared__ __align__(16) unsigned short As[128 * LDST];
    __shared__ __align__(16) unsigned short Bs[128 * LDST];
    int m0 = blockIdx.y * 128, n0 = blockIdx.x * 128;
    const unsigned short* Bt;
    const float* bias;
    unsigned short* dst;
    if (blockIdx.z == 0) { Bt = wtq; bias = bq; dst = qo; }
    else if (blockIdx.z == 1) { Bt = wtk; bias = bk; dst = ko; }
    else { Bt = wtv; bias = bv; dst = vo; }

    floatx4 acc[4][4];
    gemm_core(xb, Bt, As, Bs, m0, n0, 1024, acc);

    int tid = threadIdx.x, lane = tid & 63, wave = tid >> 6;
    int wr = wave >> 1, wc = wave & 1, quad = lane >> 4, l15 = lane & 15;
#pragma unroll
    for (int mt = 0; mt < 4; mt++)
#pragma unroll
        for (int nt = 0; nt < 4; nt++)
#pragma unroll
            for (int r = 0; r < 4; r++) {
                int rg = m0 + wr * 64 + mt * 16 + quad * 4 + r;   // token index b*S+s
                int cg = n0 + wc * 64 + nt * 16 + l15;            // feature index
                float v = acc[mt][nt][r] + bias[cg];
                int b = rg >> 11, s = rg & 2047;
                int h = cg >> 6, dk = cg & 63;
                dst[(((b * 16 + h) * 2048) + s) * 64 + dk] = f2bf(v);
            }
}

// ---------------- output GEMM: fp32 out + bias ----------------
__global__ __launch_bounds__(256) void gemm_out_kernel(
    const unsigned short* __restrict__ ob, const unsigned short* __restrict__ wto,
    const float* __restrict__ bo, float* __restrict__ out) {
    __shared__ __align__(16) unsigned short As[128 * LDST];
    __shared__ __align__(16) unsigned short Bs[128 * LDST];
    int m0 = blockIdx.y * 128, n0 = blockIdx.x * 128;
    floatx4 acc[4][4];
    gemm_core(ob, wto, As, Bs, m0, n0, 1024, acc);

    int tid = threadIdx.x, lane = tid & 63, wave = tid >> 6;
    int wr = wave >> 1, wc = wave & 1, quad = lane >> 4, l15 = lane & 15;
#pragma unroll
    for (int mt = 0; mt < 4; mt++)
#pragma unroll
        for (int nt = 0; nt < 4; nt++)
#pragma unroll
            for (int r = 0; r < 4; r++) {
                int rg = m0 + wr * 64 + mt * 16 + quad * 4 + r;
                int cg = n0 + wc * 64 + nt * 16 + l15;
                out[rg * 1024 + cg] = acc[mt][nt][r] + bo[cg];
            }
}

// ---------------- flash attention (causal), 64 q-rows per block, 4 waves ----------------
#define ALS 88  // LDS row stride (64 + 24 pad): 176B rows -> 16B aligned, 2-way banks

__global__ __launch_bounds__(256) void attn_kernel(
    const unsigned short* __restrict__ Q, const unsigned short* __restrict__ Kk,
    const unsigned short* __restrict__ V, unsigned short* __restrict__ O) {
    __shared__ __align__(16) unsigned short Ks[64 * ALS];
    __shared__ __align__(16) unsigned short Vs[64 * ALS];
    __shared__ __align__(16) unsigned short Ps[4 * 16 * ALS];

    int q0 = blockIdx.x * 64;
    int bh = blockIdx.y;
    long base = (long)bh * 2048 * 64;
    int tid = threadIdx.x, lane = tid & 63, wave = tid >> 6;
    int quad = lane >> 4, l15 = lane & 15;
    const float LOG2E = 1.44269504f;

    // Q fragments (A-layout), resident all kernel
    short8 qf[2];
    int qrow = q0 + wave * 16 + l15;
    qf[0] = *(const short8*)&Q[base + qrow * 64 + quad * 8];
    qf[1] = *(const short8*)&Q[base + qrow * 64 + 32 + quad * 8];

    float m_i[4], l_i[4];
    floatx4 oacc[4];
    floatx4 zero4 = {0.f, 0.f, 0.f, 0.f};
#pragma unroll
    for (int r = 0; r < 4; r++) { m_i[r] = -1e30f; l_i[r] = 0.f; }
#pragma unroll
    for (int st = 0; st < 4; st++) oacc[st] = zero4;

    int ktmax = q0 >> 6;
    for (int kt = 0; kt <= ktmax; kt++) {
        // stage K and V tiles [64 keys][64 dk]
#pragma unroll
        for (int p = 0; p < 2; p++) {
            int c = p * 256 + tid;         // 0..511
            int key = c >> 3;              // 0..63
            int dk0 = (c & 7) * 8;
            *(short8*)&Ks[key * ALS + dk0] = *(const short8*)&Kk[base + (kt * 64 + key) * 64 + dk0];
            *(short8*)&Vs[key * ALS + dk0] = *(const short8*)&V[base + (kt * 64 + key) * 64 + dk0];
        }
        __syncthreads();

        // scores S = Q K^T (C-layout): st = key subtile
        floatx4 sa[4];
#pragma unroll
        for (int st = 0; st < 4; st++) {
            sa[st] = zero4;
#pragma unroll
            for (int kk = 0; kk < 2; kk++) {
                short8 kf = *(short8*)&Ks[(st * 16 + l15) * ALS + kk * 32 + quad * 8];
                sa[st] = __builtin_amdgcn_mfma_f32_16x16x32_bf16(qf[kk], kf, sa[st], 0, 0, 0);
            }
        }

        // scale + causal mask
        float t[4][4];
#pragma unroll
        for (int st = 0; st < 4; st++)
#pragma unroll
            for (int r = 0; r < 4; r++) {
                int qg = q0 + wave * 16 + quad * 4 + r;
                int kg = kt * 64 + st * 16 + l15;
                float v = sa[st][r] * 0.125f;
                t[st][r] = (kg > qg) ? -1e30f : v;
            }

        // online softmax per q-row
#pragma unroll
        for (int r = 0; r < 4; r++) {
            float rm = fmaxf(fmaxf(t[0][r], t[1][r]), fmaxf(t[2][r], t[3][r]));
            rm = fmaxf(rm, __shfl_xor(rm, 1, 64));
            rm = fmaxf(rm, __shfl_xor(rm, 2, 64));
            rm = fmaxf(rm, __shfl_xor(rm, 4, 64));
            rm = fmaxf(rm, __shfl_xor(rm, 8, 64));
            float mn = fmaxf(m_i[r], rm);
            float alpha = exp2f((m_i[r] - mn) * LOG2E);
            float rs = 0.f;
#pragma unroll
            for (int st = 0; st < 4; st++) {
                float p = exp2f((t[st][r] - mn) * LOG2E);
                t[st][r] = p;
                rs += p;
            }
            rs += __shfl_xor(rs, 1, 64);
            rs += __shfl_xor(rs, 2, 64);
            rs += __shfl_xor(rs, 4, 64);
            rs += __shfl_xor(rs, 8, 64);
            l_i[r] = l_i[r] * alpha + rs;
            m_i[r] = mn;
#pragma unroll
            for (int st = 0; st < 4; st++) oacc[st][r] *= alpha;
        }

        // P: C-layout -> LDS -> A-layout (per-wave region, wave-synchronous)
#pragma unroll
        for (int st = 0; st < 4; st++)
#pragma unroll
            for (int r = 0; r < 4; r++)
                Ps[(wave * 16 + quad * 4 + r) * ALS + st * 16 + l15] = f2bf(t[st][r]);
        short8 pa[2];
        pa[0] = *(short8*)&Ps[(wave * 16 + l15) * ALS + quad * 8];
        pa[1] = *(short8*)&Ps[(wave * 16 + l15) * ALS + 32 + quad * 8];

        // O += P V  (st = dk subtile)
#pragma unroll
        for (int st = 0; st < 4; st++) {
#pragma unroll
            for (int kk = 0; kk < 2; kk++) {
                short8 vb;
#pragma unroll
                for (int j = 0; j < 8; j++)
                    vb[j] = (short)Vs[(kk * 32 + quad * 8 + j) * ALS + st * 16 + l15];
                oacc[st] = __builtin_amdgcn_mfma_f32_16x16x32_bf16(pa[kk], vb, oacc[st], 0, 0, 0);
            }
        }
        __syncthreads();
    }

    // epilogue: O[b,s,h*64+dk] bf16
    int b = bh >> 4, h = bh & 15;
#pragma unroll
    for (int st = 0; st < 4; st++)
#pragma unroll
        for (int r = 0; r < 4; r++) {
            int s = q0 + wave * 16 + quad * 4 + r;
            int dk = st * 16 + l15;
            float v = oacc[st][r] / l_i[r];
            O[((long)(b * 2048 + s)) * 1024 + h * 64 + dk] = f2bf(v);
        }
}

// ---------------- launch ----------------
extern "C" void kernel_launch(void* const* d_in, const int* in_sizes, int n_in,
                              void* d_out, int out_size, void* d_ws, size_t ws_size,
                              hipStream_t stream) {
    const float* x  = (const float*)d_in[0];
    const float* wq = (const float*)d_in[1];
    const float* bq = (const float*)d_in[2];
    const float* wk = (const float*)d_in[3];
    const float* bk = (const float*)d_in[4];
    const float* wv = (const float*)d_in[5];
    const float* bv = (const float*)d_in[6];
    const float* wo = (const float*)d_in[7];
    const float* bo = (const float*)d_in[8];
    // d_in[9] = mask (unused; causal mask computed analytically)

    char* w = (char*)d_ws;
    unsigned short* xb  = (unsigned short*)w;                    // 8M elems (16MB)
    unsigned short* wtq = (unsigned short*)(w + (16u << 20));    // 1M elems each
    unsigned short* wtk = wtq + (1u << 20);
    unsigned short* wtv = wtk + (1u << 20);
    unsigned short* wto = wtv + (1u << 20);
    unsigned short* qb  = wto + (1u << 20);                      // 8M elems each
    unsigned short* kb  = qb + (8u << 20);
    unsigned short* vb  = kb + (8u << 20);
    unsigned short* ob  = vb + (8u << 20);                       // ends at 88MB

    cvtx_kernel<<<8192, 256, 0, stream>>>(x, xb);
    dim3 tg(32, 32);
    wtrans_kernel<<<tg, 256, 0, stream>>>(wq, wtq);
    wtrans_kernel<<<tg, 256, 0, stream>>>(wk, wtk);
    wtrans_kernel<<<tg, 256, 0, stream>>>(wv, wtv);
    wtrans_kernel<<<tg, 256, 0, stream>>>(wo, wto);
    gemm_qkv_kernel<<<dim3(8, 64, 3), 256, 0, stream>>>(xb, wtq, wtk, wtv, bq, bk, bv, qb, kb, vb);
    attn_kernel<<<dim3(32, 64), 256, 0, stream>>>(qb, kb, vb, ob);
    gemm_out_kernel<<<dim3(8, 64), 256, 0, stream>>>(ob, wto, bo, (float*)d_out);
}